// Round 4
// baseline (754.032 us; speedup 1.0000x reference)
//
#include <hip/hip_runtime.h>
#include <cstdint>
#include <cmath>

typedef unsigned short u16;
typedef unsigned int u32;
typedef __bf16 bf16x8 __attribute__((ext_vector_type(8)));
typedef float f32x4 __attribute__((ext_vector_type(4)));
typedef float f32x16 __attribute__((ext_vector_type(16)));

#define DEV __device__ __forceinline__

DEV u16 f2bf(float f) {
    union { float f; unsigned u; } a; a.f = f;
    unsigned u = a.u;
    return (u16)((u + 0x7FFFu + ((u >> 16) & 1u)) >> 16);   // RNE
}

// pack two positive floats to bf16 pair (round-half-up: +0x8000 then take hi16)
DEV u32 pack2bf(float a, float b) {
    union { float f; u32 u; } ua, ub; ua.f = a; ub.f = b;
    return __builtin_amdgcn_perm(ub.u + 0x8000u, ua.u + 0x8000u, 0x07060302u);
}

DEV float fast_exp2(float x) {          // v_exp_f32 is native exp2
    float r;
    asm("v_exp_f32 %0, %1" : "=v"(r) : "v"(x));
    return r;
}

DEV void async16(void* lds, const void* g) {
    __builtin_amdgcn_global_load_lds(
        (const __attribute__((address_space(1))) unsigned int*)g,
        (__attribute__((address_space(3))) unsigned int*)lds, 16, 0, 0);
}

#define LOG2E 1.44269504088896f

// ---------------- weight transpose + bf16 cast: src f32 [K][N] -> dst bf16 [N][K]
__global__ void transpose_bf16(const float* __restrict__ src, u16* __restrict__ dst, int K, int N) {
    __shared__ float tile[32][33];
    int n0 = blockIdx.x * 32, k0 = blockIdx.y * 32;
    int tx = threadIdx.x, ty = threadIdx.y;
    #pragma unroll
    for (int i = ty; i < 32; i += 8) tile[i][tx] = src[(size_t)(k0 + i) * N + n0 + tx];
    __syncthreads();
    #pragma unroll
    for (int i = ty; i < 32; i += 8) dst[(size_t)(n0 + i) * K + k0 + tx] = f2bf(tile[tx][i]);
}

// ---------------- V transpose per bh: vb[bh][s][dh] -> vt[bh][dh][s] (u16)
__global__ __launch_bounds__(256)
void vtrans_k(const u16* __restrict__ vb, u16* __restrict__ vt) {
    __shared__ u16 t[64][66];
    int bh = blockIdx.x, s0 = blockIdx.y * 64;
    size_t base = (size_t)bh * 65536;
    int tid = threadIdx.x;
    #pragma unroll
    for (int p = 0; p < 2; p++) {
        int L = p * 256 + tid;
        int r = L >> 3, c = (L & 7) * 8;
        uint4 w = *(const uint4*)(vb + base + (size_t)(s0 + r) * 64 + c);
        *(uint4*)&t[r][c] = w;
    }
    __syncthreads();
    #pragma unroll
    for (int p = 0; p < 2; p++) {
        int L = p * 256 + tid;
        int d = L >> 3, cs = (L & 7) * 8;
        u16 tmp[8];
        #pragma unroll
        for (int k = 0; k < 8; k++) tmp[k] = t[cs + k][d];
        *(uint4*)(vt + base + (size_t)d * 1024 + s0 + cs) = *(uint4*)tmp;
    }
}

// ---------------- x + step_embed[step] -> fp32 residual + bf16 GEMM input
__global__ __launch_bounds__(256)
void add_step_k(const float* __restrict__ x, const float* __restrict__ se,
                const int* __restrict__ ts, float* __restrict__ xo, u16* __restrict__ xb) {
    int st = ts[0]; st = st < 0 ? 0 : (st > 15 ? 15 : st);
    size_t i = (size_t)blockIdx.x * 256 + threadIdx.x;
    float4 v = ((const float4*)x)[i];
    int c = (int)(i & 255);
    float4 e = ((const float4*)(se + (size_t)st * 1024))[c];
    v.x += e.x; v.y += e.y; v.z += e.z; v.w += e.w;
    ((float4*)xo)[i] = v;
    ushort4 u; u.x = f2bf(v.x); u.y = f2bf(v.y); u.z = f2bf(v.z); u.w = f2bf(v.w);
    ((ushort4*)xb)[i] = u;
}

// ---------------- bf16 GEMM, 32x32x16 MFMA, BK=64, XOR-swizzled LDS
// Block tile: 128 x (TJ*64); 4 waves as 2x2; wave-tile 64 x (TJ*32).
// EPI 0: scatter q/k/v bf16 (q scaled by 0.125*log2e). EPI 1: res = addf + C.
// EPI 2: ob0 = bf16(gelu(C)). EPI 3: res = addf + C.
template<int TJ, int EPI>
__global__ __launch_bounds__(256, TJ == 4 ? 2 : 4)
void gemm_bt(const u16* __restrict__ A, const u16* __restrict__ Bt,
             const float* __restrict__ bias, int Kdim,
             u16* __restrict__ ob0, u16* __restrict__ ob1, u16* __restrict__ ob2,
             const float* __restrict__ addf, float* __restrict__ outf) {
    constexpr int BN = TJ * 64;                  // 128 or 256
    __shared__ __align__(16) u16 lA[128 * 64];   // 16KB, row 128B = 8 chunks, swz c^(r&7)
    __shared__ __align__(16) u16 lB[BN * 64];    // 16/32KB
    const int tid = threadIdx.x, wave = tid >> 6, lane = tid & 63;
    const int m5 = lane & 31, h = lane >> 5;
    const int wm = wave >> 1, wn = wave & 1;
    const size_t m0 = (size_t)blockIdx.x * 128, n0 = (size_t)blockIdx.y * BN;
    const size_t kb = (size_t)Kdim * 2;

    f32x16 acc[2][TJ];
    #pragma unroll
    for (int i = 0; i < 2; i++)
        #pragma unroll
        for (int j = 0; j < TJ; j++)
            #pragma unroll
            for (int e = 0; e < 16; e++) acc[i][j][e] = 0.f;

    const char* Ab = (const char*)A + m0 * kb;
    const char* Bb = (const char*)Bt + n0 * kb;

    auto stageA = [&](int k0) {
        #pragma unroll
        for (int j = 0; j < 4; j++) {
            int loff = wave * 4096 + j * 1024 + lane * 16;
            int L = loff >> 4, r = L >> 3, c = L & 7, g = c ^ (r & 7);
            async16((char*)lA + loff, Ab + (size_t)r * kb + (size_t)k0 * 2 + g * 16);
        }
    };
    auto stageB = [&](int k0) {
        #pragma unroll
        for (int j = 0; j < TJ * 2; j++) {
            int loff = wave * (BN * 32) + j * 1024 + lane * 16;
            int L = loff >> 4, r = L >> 3, c = L & 7, g = c ^ (r & 7);
            async16((char*)lB + loff, Bb + (size_t)r * kb + (size_t)k0 * 2 + g * 16);
        }
    };

    stageA(0); stageB(0);
    const int r7 = m5 & 7;
    for (int k0 = 0; k0 < Kdim; k0 += 64) {
        __syncthreads();
        bf16x8 af[2][4], bfr[TJ][4];
        #pragma unroll
        for (int ti = 0; ti < 2; ti++) {
            int rowA = wm * 64 + ti * 32 + m5;
            #pragma unroll
            for (int kh = 0; kh < 4; kh++) {
                int cs = (kh * 2 + h) ^ r7;
                af[ti][kh] = *(const bf16x8*)((const char*)lA + rowA * 128 + cs * 16);
            }
        }
        #pragma unroll
        for (int tj = 0; tj < TJ; tj++) {
            int rowB = wn * (TJ * 32) + tj * 32 + m5;
            #pragma unroll
            for (int kh = 0; kh < 4; kh++) {
                int cs = (kh * 2 + h) ^ r7;
                bfr[tj][kh] = *(const bf16x8*)((const char*)lB + rowB * 128 + cs * 16);
            }
        }
        __syncthreads();
        if (k0 + 64 < Kdim) { stageA(k0 + 64); stageB(k0 + 64); }
        #pragma unroll
        for (int kh = 0; kh < 4; kh++)
            #pragma unroll
            for (int ti = 0; ti < 2; ti++)
                #pragma unroll
                for (int tj = 0; tj < TJ; tj++)
                    acc[ti][tj] = __builtin_amdgcn_mfma_f32_32x32x16_bf16(
                        af[ti][kh], bfr[tj][kh], acc[ti][tj], 0, 0, 0);
    }

    // C layout 32x32: col = lane&31, row = (reg&3) + 8*(reg>>2) + 4*(lane>>5)
    #pragma unroll
    for (int ti = 0; ti < 2; ti++) {
        #pragma unroll
        for (int tj = 0; tj < TJ; tj++) {
            size_t col = n0 + wn * (TJ * 32) + tj * 32 + m5;
            float bv = bias[col];
            #pragma unroll
            for (int g = 0; g < 4; g++) {
                #pragma unroll
                for (int r = 0; r < 4; r++) {
                    size_t row = m0 + wm * 64 + ti * 32 + 4 * h + 8 * g + r;
                    float val = acc[ti][tj][g * 4 + r] + bv;
                    if constexpr (EPI == 0) {
                        size_t b = row >> 10, s = row & 1023;
                        size_t t = col >> 10, c = col & 1023, hh = c >> 6, dh = c & 63;
                        size_t o = ((b * 16 + hh) * 1024 + s) * 64 + dh;
                        if (t == 0)      ob0[o] = f2bf(val * 0.18033688011112f); // 0.125*log2e
                        else if (t == 1) ob1[o] = f2bf(val);
                        else             ob2[o] = f2bf(val);
                    } else if constexpr (EPI == 1) {
                        size_t o = row * 1024 + col;
                        outf[o] = addf[o] + val;
                    } else if constexpr (EPI == 2) {
                        float ge = 0.5f * val * (1.f + erff(val * 0.70710678118f));
                        ob0[row * 4096 + col] = f2bf(ge);
                    } else {
                        size_t o = row * 1024 + col;
                        outf[o] = addf[o] + val;
                    }
                }
            }
        }
    }
}

// ---------------- flash attention v3: S^T layout, max-free exp2 softmax, MFMA row-sums
__global__ __launch_bounds__(256)
void attn_k(const u16* __restrict__ Q, const u16* __restrict__ K_, const u16* __restrict__ Vt,
            const float* __restrict__ relb, u16* __restrict__ Out) {
    __shared__ __align__(16) u16 sP[64 * 128];    // 16KB [qrow][kv] swz; first 8KB doubles as Q stage
    __shared__ __align__(16) u16 sK[128 * 64];    // 16KB [kv][dh] swz c8 ^ (r&7)
    __shared__ __align__(16) u16 sVt[64 * 128];   // 16KB [dh][kv] swz c16 ^ (r&15)
    __shared__ float sRel[128];

    const int tid = threadIdx.x, wave = tid >> 6, lane = tid & 63;
    const int quad = lane >> 4, l15 = lane & 15;
    const int sw8 = l15 & 7;
    const int bh = blockIdx.x, q0 = blockIdx.y * 64;
    const size_t base = (size_t)bh * 65536;

    if (tid < 127) sRel[tid] = relb[tid] * LOG2E;   // log2-domain bias

    auto stageK = [&](int kv0) {
        const char* kbp = (const char*)(K_ + base + (size_t)kv0 * 64);
        #pragma unroll
        for (int j = 0; j < 4; j++) {
            int loff = wave * 4096 + j * 1024 + lane * 16;
            int L = loff >> 4, r = L >> 3, c = L & 7, g = c ^ (r & 7);
            async16((char*)sK + loff, kbp + (size_t)r * 128 + g * 16);
        }
    };
    auto stageV = [&](int kv0) {
        const char* vbp = (const char*)(Vt + base) + (size_t)kv0 * 2;
        #pragma unroll
        for (int j = 0; j < 4; j++) {
            int loff = wave * 4096 + j * 1024 + lane * 16;
            int L = loff >> 4, r = L >> 4, c = L & 15, g = c ^ (r & 15);
            async16((char*)sVt + loff, vbp + (size_t)r * 2048 + g * 16);
        }
    };

    {   // stage Q into sP[0..8KB): row 128B, swz c8 ^ (r&7)
        const char* qb = (const char*)(Q + base + (size_t)q0 * 64);
        #pragma unroll
        for (int j = 0; j < 2; j++) {
            int loff = wave * 2048 + j * 1024 + lane * 16;
            int L = loff >> 4, r = L >> 3, c = L & 7, g = c ^ (r & 7);
            async16((char*)sP + loff, qb + (size_t)r * 128 + g * 16);
        }
    }
    stageK(0); stageV(0);
    __syncthreads();                               // all staging + sRel visible

    const int rowQ = wave * 16 + l15;              // this lane's q row (within 64-tile)
    bf16x8 aq0 = *(const bf16x8*)((const char*)sP + rowQ * 128 + ((quad ^ sw8) * 16));
    bf16x8 aq1 = *(const bf16x8*)((const char*)sP + rowQ * 128 + (((4 + quad) ^ sw8) * 16));

    bf16x8 ones;
    {
        union { short s[8]; bf16x8 v; } ou;
        #pragma unroll
        for (int i = 0; i < 8; i++) ou.s[i] = 0x3F80;  // bf16 1.0
        ones = ou.v;
    }

    f32x4 Oacc[4], lsum;
    #pragma unroll
    for (int n = 0; n < 4; n++) Oacc[n] = f32x4{0.f, 0.f, 0.f, 0.f};
    lsum = f32x4{0.f, 0.f, 0.f, 0.f};

    for (int t = 0; t < 8; t++) {
        const int kv0 = t * 128;
        // ---- S^T = K Q^T : rows = kv, cols = q (l15)
        f32x4 sc[8];
        #pragma unroll
        for (int ni = 0; ni < 8; ni++) {
            const char* kr = (const char*)sK + (ni * 16 + l15) * 128;
            bf16x8 k0f = *(const bf16x8*)(kr + ((quad ^ sw8) * 16));
            bf16x8 k1f = *(const bf16x8*)(kr + (((4 + quad) ^ sw8) * 16));
            f32x4 z = f32x4{0.f, 0.f, 0.f, 0.f};
            z = __builtin_amdgcn_mfma_f32_16x16x32_bf16(k0f, aq0, z, 0, 0, 0);
            sc[ni] = __builtin_amdgcn_mfma_f32_16x16x32_bf16(k1f, aq1, z, 0, 0, 0);
        }
        // ---- bias (log2 domain) + exp2 + pack + store P rows (b64, swizzled)
        const int qs = q0 + rowQ;
        if (kv0 >= q0 + 126) {
            float cb = sRel[0];
            #pragma unroll
            for (int ni = 0; ni < 8; ni++)
                #pragma unroll
                for (int r = 0; r < 4; r++) sc[ni][r] = fast_exp2(sc[ni][r] + cb);
        } else if (kv0 <= q0 - 190) {
            float cb = sRel[126];
            #pragma unroll
            for (int ni = 0; ni < 8; ni++)
                #pragma unroll
                for (int r = 0; r < 4; r++) sc[ni][r] = fast_exp2(sc[ni][r] + cb);
        } else {
            #pragma unroll
            for (int ni = 0; ni < 8; ni++) {
                #pragma unroll
                for (int r = 0; r < 4; r++) {
                    int ks = kv0 + ni * 16 + quad * 4 + r;
                    int rel = qs - ks + 63;
                    rel = rel < 0 ? 0 : (rel > 126 ? 126 : rel);
                    sc[ni][r] = fast_exp2(sc[ni][r] + sRel[rel]);
                }
            }
        }
        {
            char* prow = (char*)sP + rowQ * 256 + (quad & 1) * 8;
            #pragma unroll
            for (int ni = 0; ni < 8; ni++) {
                uint2 pk;
                pk.x = pack2bf(sc[ni][0], sc[ni][1]);
                pk.y = pack2bf(sc[ni][2], sc[ni][3]);
                int c16 = (ni * 2 + (quad >> 1)) ^ l15;
                *(uint2*)(prow + c16 * 16) = pk;
            }
        }
        __syncthreads();                           // sK consumed by all waves
        if (t < 7) stageK(kv0 + 128);              // overlaps PV

        // ---- O += P V ; lsum += P·1  (sP rows are wave-private: no barrier needed)
        #pragma unroll
        for (int kk = 0; kk < 4; kk++) {
            int swc = (kk * 4 + quad) ^ l15;
            bf16x8 pf = *(const bf16x8*)((const char*)sP + rowQ * 256 + swc * 16);
            lsum = __builtin_amdgcn_mfma_f32_16x16x32_bf16(pf, ones, lsum, 0, 0, 0);
            #pragma unroll
            for (int n = 0; n < 4; n++) {
                bf16x8 vf = *(const bf16x8*)((const char*)sVt + (n * 16 + l15) * 256 + swc * 16);
                Oacc[n] = __builtin_amdgcn_mfma_f32_16x16x32_bf16(pf, vf, Oacc[n], 0, 0, 0);
            }
        }
        __syncthreads();                           // sVt consumed by all waves
        if (t < 7) stageV(kv0 + 128);              // drains at next top barrier
    }

    const int b = bh >> 4, hh = bh & 15;
    #pragma unroll
    for (int r = 0; r < 4; r++) {
        float inv = 1.f / lsum[r];
        int srow = q0 + wave * 16 + quad * 4 + r;
        size_t rowg = ((size_t)b * 1024 + srow) * 1024 + hh * 64;
        #pragma unroll
        for (int n = 0; n < 4; n++) Out[rowg + n * 16 + l15] = f2bf(Oacc[n][r] * inv);
    }
}

// ---------------- LayerNorm over rows of 1024; optionally emit bf16 copy
template<bool WB>
__global__ __launch_bounds__(256)
void ln_k(const float* __restrict__ in, const float* __restrict__ g, const float* __restrict__ b,
          float* __restrict__ of, u16* __restrict__ ob) {
    __shared__ float ws1[4], ws2[4];
    int row = blockIdx.x, t = threadIdx.x;
    float4 v = ((const float4*)(in + (size_t)row * 1024))[t];
    float s = v.x + v.y + v.z + v.w;
    float s2 = v.x * v.x + v.y * v.y + v.z * v.z + v.w * v.w;
    #pragma unroll
    for (int m = 1; m < 64; m <<= 1) { s += __shfl_xor(s, m); s2 += __shfl_xor(s2, m); }
    if ((t & 63) == 0) { ws1[t >> 6] = s; ws2[t >> 6] = s2; }
    __syncthreads();
    s = ws1[0] + ws1[1] + ws1[2] + ws1[3];
    s2 = ws2[0] + ws2[1] + ws2[2] + ws2[3];
    float mean = s * (1.f / 1024.f);
    float var = s2 * (1.f / 1024.f) - mean * mean;
    float inv = rsqrtf(var + 1e-5f);
    float4 gv = ((const float4*)g)[t], bv = ((const float4*)b)[t];
    float4 o;
    o.x = (v.x - mean) * inv * gv.x + bv.x;
    o.y = (v.y - mean) * inv * gv.y + bv.y;
    o.z = (v.z - mean) * inv * gv.z + bv.z;
    o.w = (v.w - mean) * inv * gv.w + bv.w;
    ((float4*)(of + (size_t)row * 1024))[t] = o;
    if (WB) {
        ushort4 u; u.x = f2bf(o.x); u.y = f2bf(o.y); u.z = f2bf(o.z); u.w = f2bf(o.w);
        ((ushort4*)(ob + (size_t)row * 1024))[t] = u;
    }
}

extern "C" void kernel_launch(void* const* d_in, const int* in_sizes, int n_in,
                              void* d_out, int out_size, void* d_ws, size_t ws_size,
                              hipStream_t stream) {
    (void)in_sizes; (void)n_in; (void)out_size; (void)ws_size;
    const float* x          = (const float*)d_in[0];
    const float* step_embed = (const float*)d_in[1];
    const float* qkv_w      = (const float*)d_in[2];
    const float* qkv_b      = (const float*)d_in[3];
    const float* out_w      = (const float*)d_in[4];
    const float* out_b      = (const float*)d_in[5];
    const float* relb       = (const float*)d_in[6];
    const float* w1         = (const float*)d_in[7];
    const float* b1         = (const float*)d_in[8];
    const float* w2         = (const float*)d_in[9];
    const float* b2         = (const float*)d_in[10];
    const float* ln1g       = (const float*)d_in[11];
    const float* ln1b       = (const float*)d_in[12];
    const float* ln2g       = (const float*)d_in[13];
    const float* ln2b       = (const float*)d_in[14];
    const int*   tstep      = (const int*)d_in[15];
    float* out = (float*)d_out;

    char* p = (char*)d_ws;
    u16* wt_qkv = (u16*)p; p += (size_t)3072 * 1024 * 2;
    u16* wt_out = (u16*)p; p += (size_t)1024 * 1024 * 2;
    u16* wt_w1  = (u16*)p; p += (size_t)4096 * 1024 * 2;
    u16* wt_w2  = (u16*)p; p += (size_t)1024 * 4096 * 2;
    float* xse  = (float*)p; p += (size_t)8192 * 1024 * 4;
    u16* xseb   = (u16*)p; p += (size_t)8192 * 1024 * 2;
    u16* qbuf   = (u16*)p; p += (size_t)8192 * 1024 * 2;
    u16* kbuf   = (u16*)p; p += (size_t)8192 * 1024 * 2;
    u16* vbuf   = (u16*)p; p += (size_t)8192 * 1024 * 2;
    u16* attnb  = (u16*)p; p += (size_t)8192 * 1024 * 2;
    float* res1 = (float*)p; p += (size_t)8192 * 1024 * 4;
    // aliases (lifetimes disjoint):
    float* y1   = xse;
    u16*   y1b  = xseb;
    u16*   hbuf = qbuf;
    float* res2 = res1;
    u16*   vtb  = (u16*)res1;     // V^T lives [vtrans..attn]; res1 written after attn

    dim3 tb(32, 8);
    transpose_bf16<<<dim3(96, 32),  tb, 0, stream>>>(qkv_w, wt_qkv, 1024, 3072);
    transpose_bf16<<<dim3(32, 32),  tb, 0, stream>>>(out_w, wt_out, 1024, 1024);
    transpose_bf16<<<dim3(128, 32), tb, 0, stream>>>(w1, wt_w1, 1024, 4096);
    transpose_bf16<<<dim3(32, 128), tb, 0, stream>>>(w2, wt_w2, 4096, 1024);
    add_step_k<<<dim3(8192), dim3(256), 0, stream>>>(x, step_embed, tstep, xse, xseb);
    gemm_bt<4, 0><<<dim3(64, 12), dim3(256), 0, stream>>>(xseb, wt_qkv, qkv_b, 1024,
                                                          qbuf, kbuf, vbuf, (const float*)nullptr, (float*)nullptr);
    vtrans_k<<<dim3(128, 16), dim3(256), 0, stream>>>(vbuf, vtb);
    attn_k<<<dim3(128, 16), dim3(256), 0, stream>>>(qbuf, kbuf, vtb, relb, attnb);
    gemm_bt<2, 1><<<dim3(64, 8), dim3(256), 0, stream>>>(attnb, wt_out, out_b, 1024,
                                                         (u16*)nullptr, (u16*)nullptr, (u16*)nullptr, xse, res1);
    ln_k<true><<<dim3(8192), dim3(256), 0, stream>>>(res1, ln1g, ln1b, y1, y1b);
    gemm_bt<4, 2><<<dim3(64, 16), dim3(256), 0, stream>>>(y1b, wt_w1, b1, 1024,
                                                          hbuf, (u16*)nullptr, (u16*)nullptr, (const float*)nullptr, (float*)nullptr);
    gemm_bt<4, 3><<<dim3(64, 4), dim3(256), 0, stream>>>(hbuf, wt_w2, b2, 4096,
                                                         (u16*)nullptr, (u16*)nullptr, (u16*)nullptr, y1, res2);
    ln_k<false><<<dim3(8192), dim3(256), 0, stream>>>(res2, ln2g, ln2b, out, (u16*)nullptr);
}

// Round 5
// 530.242 us; speedup vs baseline: 1.4221x; 1.4221x over previous
//
#include <hip/hip_runtime.h>
#include <cstdint>
#include <cmath>

typedef unsigned short u16;
typedef unsigned int u32;
typedef __bf16 bf16x8 __attribute__((ext_vector_type(8)));
typedef float f32x4 __attribute__((ext_vector_type(4)));
typedef float f32x16 __attribute__((ext_vector_type(16)));

#define DEV __device__ __forceinline__

DEV u16 f2bf(float f) {
    union { float f; unsigned u; } a; a.f = f;
    unsigned u = a.u;
    return (u16)((u + 0x7FFFu + ((u >> 16) & 1u)) >> 16);   // RNE
}

// pack two positive floats to bf16 pair (round-half-up: +0x8000 then take hi16)
DEV u32 pack2bf(float a, float b) {
    union { float f; u32 u; } ua, ub; ua.f = a; ub.f = b;
    return __builtin_amdgcn_perm(ub.u + 0x8000u, ua.u + 0x8000u, 0x07060302u);
}

DEV float fast_exp2(float x) {          // v_exp_f32 is native exp2
    float r;
    asm("v_exp_f32 %0, %1" : "=v"(r) : "v"(x));
    return r;
}

DEV void async16(void* lds, const void* g) {
    __builtin_amdgcn_global_load_lds(
        (const __attribute__((address_space(1))) unsigned int*)g,
        (__attribute__((address_space(3))) unsigned int*)lds, 16, 0, 0);
}

#define LOG2E 1.44269504088896f

// ---------------- fused weight transpose + bf16 cast for all 4 weights
// src f32 [K][N] -> dst bf16 [N][K]; one 32x32 tile per block.
__global__ void transpose_all(const float* __restrict__ s0, u16* __restrict__ d0,
                              const float* __restrict__ s1, u16* __restrict__ d1,
                              const float* __restrict__ s2, u16* __restrict__ d2,
                              const float* __restrict__ s3, u16* __restrict__ d3) {
    __shared__ float tile[32][33];
    int b = blockIdx.x;
    const float* src; u16* dst; int N, tidx;
    if (b < 3072)      { src = s0; dst = d0; N = 3072; tidx = b; }
    else if (b < 4096) { src = s1; dst = d1; N = 1024; tidx = b - 3072; }
    else if (b < 8192) { src = s2; dst = d2; N = 4096; tidx = b - 4096; }
    else               { src = s3; dst = d3; N = 1024; tidx = b - 8192; }
    int ntx = N >> 5;
    int n0 = (tidx % ntx) * 32, k0 = (tidx / ntx) * 32;
    int K = (b >= 8192) ? 4096 : 1024;
    int tx = threadIdx.x, ty = threadIdx.y;
    #pragma unroll
    for (int i = ty; i < 32; i += 8) tile[i][tx] = src[(size_t)(k0 + i) * N + n0 + tx];
    __syncthreads();
    #pragma unroll
    for (int i = ty; i < 32; i += 8) dst[(size_t)(n0 + i) * K + k0 + tx] = f2bf(tile[tx][i]);
}

// ---------------- x + step_embed[step] -> fp32 residual + bf16 GEMM input
__global__ __launch_bounds__(256)
void add_step_k(const float* __restrict__ x, const float* __restrict__ se,
                const int* __restrict__ ts, float* __restrict__ xo, u16* __restrict__ xb) {
    int st = ts[0]; st = st < 0 ? 0 : (st > 15 ? 15 : st);
    size_t i = (size_t)blockIdx.x * 256 + threadIdx.x;
    float4 v = ((const float4*)x)[i];
    int c = (int)(i & 255);
    float4 e = ((const float4*)(se + (size_t)st * 1024))[c];
    v.x += e.x; v.y += e.y; v.z += e.z; v.w += e.w;
    ((float4*)xo)[i] = v;
    ushort4 u; u.x = f2bf(v.x); u.y = f2bf(v.y); u.z = f2bf(v.z); u.w = f2bf(v.w);
    ((ushort4*)xb)[i] = u;
}

// ---------------- bf16 GEMM, 32x32x16 MFMA, BK=64, XOR-swizzled LDS (round-3 proven cfg)
// Block 128x128, 4 waves 2x2, wave-tile 64x64.
// EPI 0: scatter q (scaled 0.125*log2e) / k / v^T. EPI 1: res = addf + C.
// EPI 2: ob0 = bf16(gelu(C)). EPI 3: res = addf + C.
template<int EPI>
__global__ __launch_bounds__(256)
void gemm_bt(const u16* __restrict__ A, const u16* __restrict__ Bt,
             const float* __restrict__ bias, int Kdim,
             u16* __restrict__ ob0, u16* __restrict__ ob1, u16* __restrict__ ob2,
             const float* __restrict__ addf, float* __restrict__ outf) {
    __shared__ __align__(16) u16 lA[128 * 64];   // 16KB, row 128B = 8 chunks, swz c^(r&7)
    __shared__ __align__(16) u16 lB[128 * 64];
    const int tid = threadIdx.x, wave = tid >> 6, lane = tid & 63;
    const int m5 = lane & 31, h = lane >> 5;
    const int wm = wave >> 1, wn = wave & 1;
    const size_t m0 = (size_t)blockIdx.x * 128, n0 = (size_t)blockIdx.y * 128;
    const size_t kb = (size_t)Kdim * 2;

    f32x16 acc[2][2];
    #pragma unroll
    for (int i = 0; i < 2; i++)
        #pragma unroll
        for (int j = 0; j < 2; j++)
            #pragma unroll
            for (int e = 0; e < 16; e++) acc[i][j][e] = 0.f;

    const char* Ab = (const char*)A + m0 * kb;
    const char* Bb = (const char*)Bt + n0 * kb;

    auto stage = [&](const char* srcbase, u16* ldsb, int k0) {
        #pragma unroll
        for (int j = 0; j < 4; j++) {
            int loff = wave * 4096 + j * 1024 + lane * 16;
            int L = loff >> 4, r = L >> 3, c = L & 7, g = c ^ (r & 7);
            async16((char*)ldsb + loff, srcbase + (size_t)r * kb + (size_t)k0 * 2 + g * 16);
        }
    };

    stage(Ab, lA, 0); stage(Bb, lB, 0);
    const int r7 = m5 & 7;
    for (int k0 = 0; k0 < Kdim; k0 += 64) {
        __syncthreads();
        bf16x8 af[2][4], bfr[2][4];
        #pragma unroll
        for (int ti = 0; ti < 2; ti++) {
            int rowA = wm * 64 + ti * 32 + m5;
            int rowB = wn * 64 + ti * 32 + m5;
            #pragma unroll
            for (int kh = 0; kh < 4; kh++) {
                int cs = (kh * 2 + h) ^ r7;
                af[ti][kh]  = *(const bf16x8*)((const char*)lA + rowA * 128 + cs * 16);
                bfr[ti][kh] = *(const bf16x8*)((const char*)lB + rowB * 128 + cs * 16);
            }
        }
        __syncthreads();
        if (k0 + 64 < Kdim) { stage(Ab, lA, k0 + 64); stage(Bb, lB, k0 + 64); }
        #pragma unroll
        for (int kh = 0; kh < 4; kh++)
            #pragma unroll
            for (int ti = 0; ti < 2; ti++)
                #pragma unroll
                for (int tj = 0; tj < 2; tj++)
                    acc[ti][tj] = __builtin_amdgcn_mfma_f32_32x32x16_bf16(
                        af[ti][kh], bfr[tj][kh], acc[ti][tj], 0, 0, 0);
    }

    // C layout 32x32: col = lane&31, row = (reg&3) + 8*(reg>>2) + 4*(lane>>5)
    #pragma unroll
    for (int ti = 0; ti < 2; ti++) {
        #pragma unroll
        for (int tj = 0; tj < 2; tj++) {
            size_t col = n0 + wn * 64 + tj * 32 + m5;
            float bv = bias[col];
            if constexpr (EPI == 0) {
                size_t t = col >> 10, c = col & 1023, hh = c >> 6, dh = c & 63;
                #pragma unroll
                for (int g = 0; g < 4; g++) {
                    size_t row0 = m0 + wm * 64 + ti * 32 + 4 * h + 8 * g;
                    size_t bq = row0 >> 10, s0 = row0 & 1023;
                    if (t == 0) {
                        #pragma unroll
                        for (int r = 0; r < 4; r++)
                            ob0[((bq * 16 + hh) * 1024 + s0 + r) * 64 + dh] =
                                f2bf((acc[ti][tj][g * 4 + r] + bv) * 0.18033688011112f);
                    } else if (t == 1) {
                        #pragma unroll
                        for (int r = 0; r < 4; r++)
                            ob1[((bq * 16 + hh) * 1024 + s0 + r) * 64 + dh] =
                                f2bf(acc[ti][tj][g * 4 + r] + bv);
                    } else {
                        // V written TRANSPOSED: vt[bh][dh][s]; 4 consecutive s -> 8B store
                        ushort4 tmp;
                        tmp.x = f2bf(acc[ti][tj][g * 4 + 0] + bv);
                        tmp.y = f2bf(acc[ti][tj][g * 4 + 1] + bv);
                        tmp.z = f2bf(acc[ti][tj][g * 4 + 2] + bv);
                        tmp.w = f2bf(acc[ti][tj][g * 4 + 3] + bv);
                        *(ushort4*)(ob2 + ((bq * 16 + hh) * 64 + dh) * 1024 + s0) = tmp;
                    }
                }
            } else {
                #pragma unroll
                for (int g = 0; g < 4; g++) {
                    #pragma unroll
                    for (int r = 0; r < 4; r++) {
                        size_t row = m0 + wm * 64 + ti * 32 + 4 * h + 8 * g + r;
                        float val = acc[ti][tj][g * 4 + r] + bv;
                        if constexpr (EPI == 1) {
                            size_t o = row * 1024 + col;
                            outf[o] = addf[o] + val;
                        } else if constexpr (EPI == 2) {
                            float ge = 0.5f * val * (1.f + erff(val * 0.70710678118f));
                            ob0[row * 4096 + col] = f2bf(ge);
                        } else {
                            size_t o = row * 1024 + col;
                            outf[o] = addf[o] + val;
                        }
                    }
                }
            }
        }
    }
}

// ---------------- flash attention v3: S^T layout, max-free exp2 softmax, MFMA row-sums
__global__ __launch_bounds__(256)
void attn_k(const u16* __restrict__ Q, const u16* __restrict__ K_, const u16* __restrict__ Vt,
            const float* __restrict__ relb, u16* __restrict__ Out) {
    __shared__ __align__(16) u16 sP[64 * 128];    // 16KB [qrow][kv] swz; first 8KB doubles as Q stage
    __shared__ __align__(16) u16 sK[128 * 64];    // 16KB [kv][dh] swz c8 ^ (r&7)
    __shared__ __align__(16) u16 sVt[64 * 128];   // 16KB [dh][kv] swz c16 ^ (r&15)
    __shared__ float sRel[128];

    const int tid = threadIdx.x, wave = tid >> 6, lane = tid & 63;
    const int quad = lane >> 4, l15 = lane & 15;
    const int sw8 = l15 & 7;
    const int bh = blockIdx.x, q0 = blockIdx.y * 64;
    const size_t base = (size_t)bh * 65536;

    if (tid < 127) sRel[tid] = relb[tid] * LOG2E;   // log2-domain bias

    auto stageK = [&](int kv0) {
        const char* kbp = (const char*)(K_ + base + (size_t)kv0 * 64);
        #pragma unroll
        for (int j = 0; j < 4; j++) {
            int loff = wave * 4096 + j * 1024 + lane * 16;
            int L = loff >> 4, r = L >> 3, c = L & 7, g = c ^ (r & 7);
            async16((char*)sK + loff, kbp + (size_t)r * 128 + g * 16);
        }
    };
    auto stageV = [&](int kv0) {
        const char* vbp = (const char*)(Vt + base) + (size_t)kv0 * 2;
        #pragma unroll
        for (int j = 0; j < 4; j++) {
            int loff = wave * 4096 + j * 1024 + lane * 16;
            int L = loff >> 4, r = L >> 4, c = L & 15, g = c ^ (r & 15);
            async16((char*)sVt + loff, vbp + (size_t)r * 2048 + g * 16);
        }
    };

    {   // stage Q into sP[0..8KB): row 128B, swz c8 ^ (r&7)
        const char* qb = (const char*)(Q + base + (size_t)q0 * 64);
        #pragma unroll
        for (int j = 0; j < 2; j++) {
            int loff = wave * 2048 + j * 1024 + lane * 16;
            int L = loff >> 4, r = L >> 3, c = L & 7, g = c ^ (r & 7);
            async16((char*)sP + loff, qb + (size_t)r * 128 + g * 16);
        }
    }
    stageK(0); stageV(0);
    __syncthreads();                               // all staging + sRel visible

    const int rowQ = wave * 16 + l15;              // this lane's q row (within 64-tile)
    bf16x8 aq0 = *(const bf16x8*)((const char*)sP + rowQ * 128 + ((quad ^ sw8) * 16));
    bf16x8 aq1 = *(const bf16x8*)((const char*)sP + rowQ * 128 + (((4 + quad) ^ sw8) * 16));

    bf16x8 ones;
    {
        union { short s[8]; bf16x8 v; } ou;
        #pragma unroll
        for (int i = 0; i < 8; i++) ou.s[i] = 0x3F80;  // bf16 1.0
        ones = ou.v;
    }

    f32x4 Oacc[4], lsum;
    #pragma unroll
    for (int n = 0; n < 4; n++) Oacc[n] = f32x4{0.f, 0.f, 0.f, 0.f};
    lsum = f32x4{0.f, 0.f, 0.f, 0.f};

    for (int t = 0; t < 8; t++) {
        const int kv0 = t * 128;
        // ---- S^T = K Q^T : rows = kv, cols = q (l15)
        f32x4 sc[8];
        #pragma unroll
        for (int ni = 0; ni < 8; ni++) {
            const char* kr = (const char*)sK + (ni * 16 + l15) * 128;
            bf16x8 k0f = *(const bf16x8*)(kr + ((quad ^ sw8) * 16));
            bf16x8 k1f = *(const bf16x8*)(kr + (((4 + quad) ^ sw8) * 16));
            f32x4 z = f32x4{0.f, 0.f, 0.f, 0.f};
            z = __builtin_amdgcn_mfma_f32_16x16x32_bf16(k0f, aq0, z, 0, 0, 0);
            sc[ni] = __builtin_amdgcn_mfma_f32_16x16x32_bf16(k1f, aq1, z, 0, 0, 0);
        }
        // ---- bias (log2 domain) + exp2 + pack + store P rows (b64, swizzled)
        const int qs = q0 + rowQ;
        if (kv0 >= q0 + 126) {
            float cb = sRel[0];
            #pragma unroll
            for (int ni = 0; ni < 8; ni++)
                #pragma unroll
                for (int r = 0; r < 4; r++) sc[ni][r] = fast_exp2(sc[ni][r] + cb);
        } else if (kv0 <= q0 - 190) {
            float cb = sRel[126];
            #pragma unroll
            for (int ni = 0; ni < 8; ni++)
                #pragma unroll
                for (int r = 0; r < 4; r++) sc[ni][r] = fast_exp2(sc[ni][r] + cb);
        } else {
            #pragma unroll
            for (int ni = 0; ni < 8; ni++) {
                #pragma unroll
                for (int r = 0; r < 4; r++) {
                    int ks = kv0 + ni * 16 + quad * 4 + r;
                    int rel = qs - ks + 63;
                    rel = rel < 0 ? 0 : (rel > 126 ? 126 : rel);
                    sc[ni][r] = fast_exp2(sc[ni][r] + sRel[rel]);
                }
            }
        }
        {
            char* prow = (char*)sP + rowQ * 256 + (quad & 1) * 8;
            #pragma unroll
            for (int ni = 0; ni < 8; ni++) {
                uint2 pk;
                pk.x = pack2bf(sc[ni][0], sc[ni][1]);
                pk.y = pack2bf(sc[ni][2], sc[ni][3]);
                int c16 = (ni * 2 + (quad >> 1)) ^ l15;
                *(uint2*)(prow + c16 * 16) = pk;
            }
        }
        __syncthreads();                           // sK consumed by all waves
        if (t < 7) stageK(kv0 + 128);              // overlaps PV

        // ---- O += P V ; lsum += P·1  (sP rows are wave-private: no barrier needed)
        #pragma unroll
        for (int kk = 0; kk < 4; kk++) {
            int swc = (kk * 4 + quad) ^ l15;
            bf16x8 pf = *(const bf16x8*)((const char*)sP + rowQ * 256 + swc * 16);
            lsum = __builtin_amdgcn_mfma_f32_16x16x32_bf16(pf, ones, lsum, 0, 0, 0);
            #pragma unroll
            for (int n = 0; n < 4; n++) {
                bf16x8 vf = *(const bf16x8*)((const char*)sVt + (n * 16 + l15) * 256 + swc * 16);
                Oacc[n] = __builtin_amdgcn_mfma_f32_16x16x32_bf16(pf, vf, Oacc[n], 0, 0, 0);
            }
        }
        __syncthreads();                           // sVt consumed by all waves
        if (t < 7) stageV(kv0 + 128);              // drains at next top barrier
    }

    const int b = bh >> 4, hh = bh & 15;
    #pragma unroll
    for (int r = 0; r < 4; r++) {
        float inv = 1.f / lsum[r];
        int srow = q0 + wave * 16 + quad * 4 + r;
        size_t rowg = ((size_t)b * 1024 + srow) * 1024 + hh * 64;
        #pragma unroll
        for (int n = 0; n < 4; n++) Out[rowg + n * 16 + l15] = f2bf(Oacc[n][r] * inv);
    }
}

// ---------------- LayerNorm over rows of 1024; optionally emit bf16 copy
template<bool WB>
__global__ __launch_bounds__(256)
void ln_k(const float* __restrict__ in, const float* __restrict__ g, const float* __restrict__ b,
          float* __restrict__ of, u16* __restrict__ ob) {
    __shared__ float ws1[4], ws2[4];
    int row = blockIdx.x, t = threadIdx.x;
    float4 v = ((const float4*)(in + (size_t)row * 1024))[t];
    float s = v.x + v.y + v.z + v.w;
    float s2 = v.x * v.x + v.y * v.y + v.z * v.z + v.w * v.w;
    #pragma unroll
    for (int m = 1; m < 64; m <<= 1) { s += __shfl_xor(s, m); s2 += __shfl_xor(s2, m); }
    if ((t & 63) == 0) { ws1[t >> 6] = s; ws2[t >> 6] = s2; }
    __syncthreads();
    s = ws1[0] + ws1[1] + ws1[2] + ws1[3];
    s2 = ws2[0] + ws2[1] + ws2[2] + ws2[3];
    float mean = s * (1.f / 1024.f);
    float var = s2 * (1.f / 1024.f) - mean * mean;
    float inv = rsqrtf(var + 1e-5f);
    float4 gv = ((const float4*)g)[t], bv = ((const float4*)b)[t];
    float4 o;
    o.x = (v.x - mean) * inv * gv.x + bv.x;
    o.y = (v.y - mean) * inv * gv.y + bv.y;
    o.z = (v.z - mean) * inv * gv.z + bv.z;
    o.w = (v.w - mean) * inv * gv.w + bv.w;
    ((float4*)(of + (size_t)row * 1024))[t] = o;
    if (WB) {
        ushort4 u; u.x = f2bf(o.x); u.y = f2bf(o.y); u.z = f2bf(o.z); u.w = f2bf(o.w);
        ((ushort4*)(ob + (size_t)row * 1024))[t] = u;
    }
}

extern "C" void kernel_launch(void* const* d_in, const int* in_sizes, int n_in,
                              void* d_out, int out_size, void* d_ws, size_t ws_size,
                              hipStream_t stream) {
    (void)in_sizes; (void)n_in; (void)out_size; (void)ws_size;
    const float* x          = (const float*)d_in[0];
    const float* step_embed = (const float*)d_in[1];
    const float* qkv_w      = (const float*)d_in[2];
    const float* qkv_b      = (const float*)d_in[3];
    const float* out_w      = (const float*)d_in[4];
    const float* out_b      = (const float*)d_in[5];
    const float* relb       = (const float*)d_in[6];
    const float* w1         = (const float*)d_in[7];
    const float* b1         = (const float*)d_in[8];
    const float* w2         = (const float*)d_in[9];
    const float* b2         = (const float*)d_in[10];
    const float* ln1g       = (const float*)d_in[11];
    const float* ln1b       = (const float*)d_in[12];
    const float* ln2g       = (const float*)d_in[13];
    const float* ln2b       = (const float*)d_in[14];
    const int*   tstep      = (const int*)d_in[15];
    float* out = (float*)d_out;

    char* p = (char*)d_ws;
    u16* wt_qkv = (u16*)p; p += (size_t)3072 * 1024 * 2;
    u16* wt_out = (u16*)p; p += (size_t)1024 * 1024 * 2;
    u16* wt_w1  = (u16*)p; p += (size_t)4096 * 1024 * 2;
    u16* wt_w2  = (u16*)p; p += (size_t)1024 * 4096 * 2;
    float* xse  = (float*)p; p += (size_t)8192 * 1024 * 4;
    u16* xseb   = (u16*)p; p += (size_t)8192 * 1024 * 2;
    u16* qbuf   = (u16*)p; p += (size_t)8192 * 1024 * 2;
    u16* kbuf   = (u16*)p; p += (size_t)8192 * 1024 * 2;
    u16* attnb  = (u16*)p; p += (size_t)8192 * 1024 * 2;
    float* res1 = (float*)p; p += (size_t)8192 * 1024 * 4;
    // aliases (lifetimes disjoint):
    float* y1   = xse;            // x_se dead after out-proj residual
    u16*   y1b  = xseb;           // x_se_bf16 dead after QKV GEMM
    u16*   hbuf = qbuf;           // q/k/attn dead after out-proj GEMM
    float* res2 = res1;           // res1 dead after LN1
    u16*   vtb  = (u16*)res1;     // V^T (written by QKV epilogue) lives until attn; res1 written after attn

    transpose_all<<<dim3(12288), dim3(32, 8), 0, stream>>>(qkv_w, wt_qkv, out_w, wt_out,
                                                           w1, wt_w1, w2, wt_w2);
    add_step_k<<<dim3(8192), dim3(256), 0, stream>>>(x, step_embed, tstep, xse, xseb);
    gemm_bt<0><<<dim3(64, 24), dim3(256), 0, stream>>>(xseb, wt_qkv, qkv_b, 1024,
                                                       qbuf, kbuf, vtb, (const float*)nullptr, (float*)nullptr);
    attn_k<<<dim3(128, 16), dim3(256), 0, stream>>>(qbuf, kbuf, vtb, relb, attnb);
    gemm_bt<1><<<dim3(64, 8), dim3(256), 0, stream>>>(attnb, wt_out, out_b, 1024,
                                                      (u16*)nullptr, (u16*)nullptr, (u16*)nullptr, xse, res1);
    ln_k<true><<<dim3(8192), dim3(256), 0, stream>>>(res1, ln1g, ln1b, y1, y1b);
    gemm_bt<2><<<dim3(64, 32), dim3(256), 0, stream>>>(y1b, wt_w1, b1, 1024,
                                                       hbuf, (u16*)nullptr, (u16*)nullptr, (const float*)nullptr, (float*)nullptr);
    gemm_bt<3><<<dim3(64, 8), dim3(256), 0, stream>>>(hbuf, wt_w2, b2, 4096,
                                                      (u16*)nullptr, (u16*)nullptr, (u16*)nullptr, y1, res2);
    ln_k<false><<<dim3(8192), dim3(256), 0, stream>>>(res2, ln2g, ln2b, out, (u16*)nullptr);
}

// Round 6
// 522.870 us; speedup vs baseline: 1.4421x; 1.0141x over previous
//
#include <hip/hip_runtime.h>
#include <cstdint>
#include <cmath>

typedef unsigned short u16;
typedef unsigned int u32;
typedef __bf16 bf16x8 __attribute__((ext_vector_type(8)));
typedef float f32x4 __attribute__((ext_vector_type(4)));
typedef float f32x16 __attribute__((ext_vector_type(16)));

#define DEV __device__ __forceinline__

DEV u16 f2bf(float f) {
    union { float f; unsigned u; } a; a.f = f;
    unsigned u = a.u;
    return (u16)((u + 0x7FFFu + ((u >> 16) & 1u)) >> 16);   // RNE
}

// pack two positive floats to bf16 pair (round-half-up: +0x8000 then take hi16)
DEV u32 pack2bf(float a, float b) {
    union { float f; u32 u; } ua, ub; ua.f = a; ub.f = b;
    return __builtin_amdgcn_perm(ub.u + 0x8000u, ua.u + 0x8000u, 0x07060302u);
}

DEV float fast_exp2(float x) {          // v_exp_f32 is native exp2
    float r;
    asm("v_exp_f32 %0, %1" : "=v"(r) : "v"(x));
    return r;
}

DEV void async16(void* lds, const void* g) {
    __builtin_amdgcn_global_load_lds(
        (const __attribute__((address_space(1))) unsigned int*)g,
        (__attribute__((address_space(3))) unsigned int*)lds, 16, 0, 0);
}

#define LOG2E 1.44269504088896f

// ---------------- fused: weight transposes (blocks 0..12287) + step-embed add (blocks 12288+)
__global__ __launch_bounds__(256)
void prep_k(const float* __restrict__ s0, u16* __restrict__ d0,
            const float* __restrict__ s1, u16* __restrict__ d1,
            const float* __restrict__ s2, u16* __restrict__ d2,
            const float* __restrict__ s3, u16* __restrict__ d3,
            const float* __restrict__ x, const float* __restrict__ se,
            const int* __restrict__ ts, float* __restrict__ xo, u16* __restrict__ xb) {
    int b = blockIdx.x, tid = threadIdx.x;
    if (b < 12288) {
        __shared__ float tile[32][33];
        const float* src; u16* dst; int N, tidx;
        if (b < 3072)      { src = s0; dst = d0; N = 3072; tidx = b; }
        else if (b < 4096) { src = s1; dst = d1; N = 1024; tidx = b - 3072; }
        else if (b < 8192) { src = s2; dst = d2; N = 4096; tidx = b - 4096; }
        else               { src = s3; dst = d3; N = 1024; tidx = b - 8192; }
        int ntx = N >> 5;
        int n0 = (tidx % ntx) * 32, k0 = (tidx / ntx) * 32;
        int K = (b >= 8192) ? 4096 : 1024;
        int tx = tid & 31, ty = tid >> 5;
        #pragma unroll
        for (int i = ty; i < 32; i += 8) tile[i][tx] = src[(size_t)(k0 + i) * N + n0 + tx];
        __syncthreads();
        #pragma unroll
        for (int i = ty; i < 32; i += 8) dst[(size_t)(n0 + i) * K + k0 + tx] = f2bf(tile[tx][i]);
    } else {
        int st = ts[0]; st = st < 0 ? 0 : (st > 15 ? 15 : st);
        size_t i = (size_t)(b - 12288) * 256 + tid;
        float4 v = ((const float4*)x)[i];
        int c = (int)(i & 255);
        float4 e = ((const float4*)(se + (size_t)st * 1024))[c];
        v.x += e.x; v.y += e.y; v.z += e.z; v.w += e.w;
        ((float4*)xo)[i] = v;
        ushort4 u; u.x = f2bf(v.x); u.y = f2bf(v.y); u.z = f2bf(v.z); u.w = f2bf(v.w);
        ((ushort4*)xb)[i] = u;
    }
}

// ---------------- bf16 GEMM, 32x32x16 MFMA, BK=64, XOR-swizzled LDS (round-3 proven cfg)
// Block 128x128, 4 waves 2x2, wave-tile 64x64.
// EPI 0: scatter q (scaled 0.125*log2e) / k / v^T. EPI 1: res = addf + C.
// EPI 2: ob0 = bf16(gelu(C)). EPI 3: res = addf + C.
template<int EPI>
__global__ __launch_bounds__(256)
void gemm_bt(const u16* __restrict__ A, const u16* __restrict__ Bt,
             const float* __restrict__ bias, int Kdim,
             u16* __restrict__ ob0, u16* __restrict__ ob1, u16* __restrict__ ob2,
             const float* __restrict__ addf, float* __restrict__ outf) {
    __shared__ __align__(16) u16 lA[128 * 64];   // 16KB, row 128B = 8 chunks, swz c^(r&7)
    __shared__ __align__(16) u16 lB[128 * 64];
    const int tid = threadIdx.x, wave = tid >> 6, lane = tid & 63;
    const int m5 = lane & 31, h = lane >> 5;
    const int wm = wave >> 1, wn = wave & 1;
    const size_t m0 = (size_t)blockIdx.x * 128, n0 = (size_t)blockIdx.y * 128;
    const size_t kb = (size_t)Kdim * 2;

    f32x16 acc[2][2];
    #pragma unroll
    for (int i = 0; i < 2; i++)
        #pragma unroll
        for (int j = 0; j < 2; j++)
            #pragma unroll
            for (int e = 0; e < 16; e++) acc[i][j][e] = 0.f;

    const char* Ab = (const char*)A + m0 * kb;
    const char* Bb = (const char*)Bt + n0 * kb;

    auto stage = [&](const char* srcbase, u16* ldsb, int k0) {
        #pragma unroll
        for (int j = 0; j < 4; j++) {
            int loff = wave * 4096 + j * 1024 + lane * 16;
            int L = loff >> 4, r = L >> 3, c = L & 7, g = c ^ (r & 7);
            async16((char*)ldsb + loff, srcbase + (size_t)r * kb + (size_t)k0 * 2 + g * 16);
        }
    };

    stage(Ab, lA, 0); stage(Bb, lB, 0);
    const int r7 = m5 & 7;
    for (int k0 = 0; k0 < Kdim; k0 += 64) {
        __syncthreads();
        bf16x8 af[2][4], bfr[2][4];
        #pragma unroll
        for (int ti = 0; ti < 2; ti++) {
            int rowA = wm * 64 + ti * 32 + m5;
            int rowB = wn * 64 + ti * 32 + m5;
            #pragma unroll
            for (int kh = 0; kh < 4; kh++) {
                int cs = (kh * 2 + h) ^ r7;
                af[ti][kh]  = *(const bf16x8*)((const char*)lA + rowA * 128 + cs * 16);
                bfr[ti][kh] = *(const bf16x8*)((const char*)lB + rowB * 128 + cs * 16);
            }
        }
        __syncthreads();
        if (k0 + 64 < Kdim) { stage(Ab, lA, k0 + 64); stage(Bb, lB, k0 + 64); }
        #pragma unroll
        for (int kh = 0; kh < 4; kh++)
            #pragma unroll
            for (int ti = 0; ti < 2; ti++)
                #pragma unroll
                for (int tj = 0; tj < 2; tj++)
                    acc[ti][tj] = __builtin_amdgcn_mfma_f32_32x32x16_bf16(
                        af[ti][kh], bfr[tj][kh], acc[ti][tj], 0, 0, 0);
    }

    // C layout 32x32: col = lane&31, row = (reg&3) + 8*(reg>>2) + 4*(lane>>5)
    #pragma unroll
    for (int ti = 0; ti < 2; ti++) {
        #pragma unroll
        for (int tj = 0; tj < 2; tj++) {
            size_t col = n0 + wn * 64 + tj * 32 + m5;
            float bv = bias[col];
            if constexpr (EPI == 0) {
                size_t t = col >> 10, c = col & 1023, hh = c >> 6, dh = c & 63;
                #pragma unroll
                for (int g = 0; g < 4; g++) {
                    size_t row0 = m0 + wm * 64 + ti * 32 + 4 * h + 8 * g;
                    size_t bq = row0 >> 10, s0 = row0 & 1023;
                    if (t == 0) {
                        #pragma unroll
                        for (int r = 0; r < 4; r++)
                            ob0[((bq * 16 + hh) * 1024 + s0 + r) * 64 + dh] =
                                f2bf((acc[ti][tj][g * 4 + r] + bv) * 0.18033688011112f);
                    } else if (t == 1) {
                        #pragma unroll
                        for (int r = 0; r < 4; r++)
                            ob1[((bq * 16 + hh) * 1024 + s0 + r) * 64 + dh] =
                                f2bf(acc[ti][tj][g * 4 + r] + bv);
                    } else {
                        // V written TRANSPOSED: vt[bh][dh][s]; 4 consecutive s -> 8B store
                        ushort4 tmp;
                        tmp.x = f2bf(acc[ti][tj][g * 4 + 0] + bv);
                        tmp.y = f2bf(acc[ti][tj][g * 4 + 1] + bv);
                        tmp.z = f2bf(acc[ti][tj][g * 4 + 2] + bv);
                        tmp.w = f2bf(acc[ti][tj][g * 4 + 3] + bv);
                        *(ushort4*)(ob2 + ((bq * 16 + hh) * 64 + dh) * 1024 + s0) = tmp;
                    }
                }
            } else {
                #pragma unroll
                for (int g = 0; g < 4; g++) {
                    #pragma unroll
                    for (int r = 0; r < 4; r++) {
                        size_t row = m0 + wm * 64 + ti * 32 + 4 * h + 8 * g + r;
                        float val = acc[ti][tj][g * 4 + r] + bv;
                        if constexpr (EPI == 1) {
                            size_t o = row * 1024 + col;
                            outf[o] = addf[o] + val;
                        } else if constexpr (EPI == 2) {
                            float ge = 0.5f * val * (1.f + erff(val * 0.70710678118f));
                            ob0[row * 4096 + col] = f2bf(ge);
                        } else {
                            size_t o = row * 1024 + col;
                            outf[o] = addf[o] + val;
                        }
                    }
                }
            }
        }
    }
}

// ---------------- flash attention v4: 128-q blocks, kv-split S-phase, (q,dh)-split PV
// S^T via 32x32x16 MFMA (no K/Q read duplication), max-free exp2 softmax,
// P through LDS with h-partner shfl packing, VALU lsum.
__global__ __launch_bounds__(256, 2)
void attn_k(const u16* __restrict__ Q, const u16* __restrict__ K_, const u16* __restrict__ Vt,
            const float* __restrict__ relb, u16* __restrict__ Out) {
    __shared__ __align__(16) u16 sP[128 * 128];   // 32KB [q][kv] rows 256B, swz c16^(q&15); first 16KB = Q stage
    __shared__ __align__(16) u16 sK[128 * 64];    // 16KB [kv][dh] rows 128B, swz c8^(kv&7)
    __shared__ __align__(16) u16 sVt[64 * 128];   // 16KB [dh][kv] rows 256B, swz c16^(dh&15)
    __shared__ float sL[4][128];
    __shared__ float sLinv[128];
    __shared__ float sRel[128];

    const int tid = threadIdx.x, wave = tid >> 6, lane = tid & 63;
    const int m5 = lane & 31, h = lane >> 5;
    const int bh = blockIdx.x, q0 = blockIdx.y * 128;
    const size_t base = (size_t)bh * 65536;

    if (tid < 127) sRel[tid] = relb[tid] * LOG2E;   // log2-domain bias

    auto stageK = [&](int kv0) {
        const char* kbp = (const char*)(K_ + base + (size_t)kv0 * 64);
        #pragma unroll
        for (int j = 0; j < 4; j++) {
            int loff = wave * 4096 + j * 1024 + lane * 16;
            int L = loff >> 4, r = L >> 3, c = L & 7, g = c ^ (r & 7);
            async16((char*)sK + loff, kbp + (size_t)r * 128 + g * 16);
        }
    };
    auto stageV = [&](int kv0) {
        const char* vbp = (const char*)(Vt + base) + (size_t)kv0 * 2;
        #pragma unroll
        for (int j = 0; j < 4; j++) {
            int loff = wave * 4096 + j * 1024 + lane * 16;
            int L = loff >> 4, r = L >> 4, c = L & 15, g = c ^ (r & 15);
            async16((char*)sVt + loff, vbp + (size_t)r * 2048 + g * 16);
        }
    };

    {   // stage Q rows q0..q0+127 into sP[0..16KB): [q][dh] rows 128B, swz c8^(q&7)
        const char* qb = (const char*)(Q + base + (size_t)q0 * 64);
        #pragma unroll
        for (int j = 0; j < 4; j++) {
            int loff = wave * 4096 + j * 1024 + lane * 16;
            int L = loff >> 4, r = L >> 3, c = L & 7, g = c ^ (r & 7);
            async16((char*)sP + loff, qb + (size_t)r * 128 + g * 16);
        }
    }
    stageK(0); stageV(0);
    __syncthreads();                               // staging + sRel visible

    // persistent Q B-fragments: qf[qt][s] : n = qt*32+m5, dh-run = 16s + 8h
    bf16x8 qf[4][4];
    #pragma unroll
    for (int qt = 0; qt < 4; qt++) {
        int row = qt * 32 + m5;
        #pragma unroll
        for (int s = 0; s < 4; s++) {
            int cs = (2 * s + h) ^ (m5 & 7);
            qf[qt][s] = *(const bf16x8*)((const char*)sP + row * 128 + cs * 16);
        }
    }
    __syncthreads();                               // Q frags read; sP reusable for P

    const int qh = wave >> 1, dhh = wave & 1;      // PV-phase role
    f32x16 Oacc[2];
    #pragma unroll
    for (int i = 0; i < 2; i++)
        #pragma unroll
        for (int e = 0; e < 16; e++) Oacc[i][e] = 0.f;
    float lsum[4] = {0.f, 0.f, 0.f, 0.f};

    for (int t = 0; t < 8; t++) {
        const int kv0 = t * 128;
        // ---- S-phase: wave handles kv rows [32*wave, +32), all 128 q
        const int kvr = wave * 32 + m5;
        bf16x8 kf[4];
        #pragma unroll
        for (int s = 0; s < 4; s++) {
            int cs = (2 * s + h) ^ (m5 & 7);
            kf[s] = *(const bf16x8*)((const char*)sK + kvr * 128 + cs * 16);
        }
        f32x16 sc[4];
        #pragma unroll
        for (int qt = 0; qt < 4; qt++)
            #pragma unroll
            for (int e = 0; e < 16; e++) sc[qt][e] = 0.f;
        #pragma unroll
        for (int s = 0; s < 4; s++)
            #pragma unroll
            for (int qt = 0; qt < 4; qt++)
                sc[qt] = __builtin_amdgcn_mfma_f32_32x32x16_bf16(kf[s], qf[qt][s], sc[qt], 0, 0, 0);

        // ---- bias + exp2 (log2 domain), lsum accumulate, pack, h-exchange, P store
        const int kvb = kv0 + wave * 32 + 4 * h;   // + 8g + r
        const bool far_lo = (kv0 >= q0 + 190);     // all rel clamp to 0
        const bool far_hi = (kv0 <= q0 - 190);     // all rel clamp to 126
        #pragma unroll
        for (int qt = 0; qt < 4; qt++) {
            const int qs = q0 + qt * 32 + m5;
            if (far_lo || far_hi) {
                float cb = far_lo ? sRel[0] : sRel[126];
                #pragma unroll
                for (int e = 0; e < 16; e++) sc[qt][e] = fast_exp2(sc[qt][e] + cb);
            } else {
                int relbase = qs - kvb + 63;
                #pragma unroll
                for (int g = 0; g < 4; g++)
                    #pragma unroll
                    for (int r = 0; r < 4; r++) {
                        int rel = relbase - 8 * g - r;
                        rel = rel < 0 ? 0 : (rel > 126 ? 126 : rel);
                        sc[qt][4 * g + r] = fast_exp2(sc[qt][4 * g + r] + sRel[rel]);
                    }
            }
            #pragma unroll
            for (int e = 0; e < 16; e++) lsum[qt] += sc[qt][e];
            // pack pairs: pk[g][j] = bf16(sc[4g+2j]),bf16(sc[4g+2j+1])
            u32 pk[4][2];
            #pragma unroll
            for (int g = 0; g < 4; g++) {
                pk[g][0] = pack2bf(sc[qt][4 * g + 0], sc[qt][4 * g + 1]);
                pk[g][1] = pack2bf(sc[qt][4 * g + 2], sc[qt][4 * g + 3]);
            }
            // h-partner exchange: lane h sends pk[2u+1-h], receives partner's pk[2u+h]
            const int q = qt * 32 + m5;
            char* prow = (char*)sP + q * 256;
            #pragma unroll
            for (int u = 0; u < 2; u++) {
                u32 s0 = h ? pk[2 * u][0] : pk[2 * u + 1][0];
                u32 s1 = h ? pk[2 * u][1] : pk[2 * u + 1][1];
                u32 r0 = __shfl_xor((int)s0, 32);
                u32 r1 = __shfl_xor((int)s1, 32);
                uint4 w;
                if (h == 0) { w.x = pk[2 * u][0]; w.y = pk[2 * u][1]; w.z = r0; w.w = r1; }
                else        { w.x = r0; w.y = r1; w.z = pk[2 * u + 1][0]; w.w = pk[2 * u + 1][1]; }
                int c16 = (4 * wave + 2 * u + h) ^ (q & 15);
                *(uint4*)(prow + c16 * 16) = w;
            }
        }
        __syncthreads();                           // P visible; sK consumed; stageV(t) drained
        if (t < 7) stageK(kv0 + 128);              // in flight during PV

        // ---- PV: wave computes O[q 64*qh..+64][dh 32*dhh..+32]
        #pragma unroll
        for (int s = 0; s < 8; s++) {
            int dh = dhh * 32 + m5;
            int cv = (2 * s + h) ^ (dh & 15);
            bf16x8 vf = *(const bf16x8*)((const char*)sVt + dh * 256 + cv * 16);
            #pragma unroll
            for (int qt = 0; qt < 2; qt++) {
                int q = qh * 64 + qt * 32 + m5;
                int cp = (2 * s + h) ^ (q & 15);
                bf16x8 pf = *(const bf16x8*)((const char*)sP + q * 256 + cp * 16);
                Oacc[qt] = __builtin_amdgcn_mfma_f32_32x32x16_bf16(pf, vf, Oacc[qt], 0, 0, 0);
            }
        }
        __syncthreads();                           // PV done: sP/sVt consumed; stageK drained
        if (t < 7) stageV(kv0 + 128);              // in flight during next S-phase
    }

    // ---- lsum reduce: merge h-partners, per-wave write, cross-wave sum
    #pragma unroll
    for (int qt = 0; qt < 4; qt++) lsum[qt] += __shfl_xor(lsum[qt], 32);
    if (h == 0) {
        #pragma unroll
        for (int qt = 0; qt < 4; qt++) sL[wave][qt * 32 + m5] = lsum[qt];
    }
    __syncthreads();
    if (tid < 128) sLinv[tid] = 1.f / (sL[0][tid] + sL[1][tid] + sL[2][tid] + sL[3][tid]);
    __syncthreads();

    // ---- epilogue: C layout col=dh, row = qt*32 + 4h + 8g + r (within wave's 64-q half)
    const int b = bh >> 4, hh = bh & 15;
    const int dh = dhh * 32 + m5;
    #pragma unroll
    for (int qt = 0; qt < 2; qt++) {
        #pragma unroll
        for (int g = 0; g < 4; g++) {
            #pragma unroll
            for (int r = 0; r < 4; r++) {
                int rl = qh * 64 + qt * 32 + 4 * h + 8 * g + r;
                float val = Oacc[qt][4 * g + r] * sLinv[rl];
                size_t s = (size_t)(q0 + rl);
                Out[((size_t)b * 1024 + s) * 1024 + hh * 64 + dh] = f2bf(val);
            }
        }
    }
}

// ---------------- LayerNorm over rows of 1024; optionally emit bf16 copy
template<bool WB>
__global__ __launch_bounds__(256)
void ln_k(const float* __restrict__ in, const float* __restrict__ g, const float* __restrict__ b,
          float* __restrict__ of, u16* __restrict__ ob) {
    __shared__ float ws1[4], ws2[4];
    int row = blockIdx.x, t = threadIdx.x;
    float4 v = ((const float4*)(in + (size_t)row * 1024))[t];
    float s = v.x + v.y + v.z + v.w;
    float s2 = v.x * v.x + v.y * v.y + v.z * v.z + v.w * v.w;
    #pragma unroll
    for (int m = 1; m < 64; m <<= 1) { s += __shfl_xor(s, m); s2 += __shfl_xor(s2, m); }
    if ((t & 63) == 0) { ws1[t >> 6] = s; ws2[t >> 6] = s2; }
    __syncthreads();
    s = ws1[0] + ws1[1] + ws1[2] + ws1[3];
    s2 = ws2[0] + ws2[1] + ws2[2] + ws2[3];
    float mean = s * (1.f / 1024.f);
    float var = s2 * (1.f / 1024.f) - mean * mean;
    float inv = rsqrtf(var + 1e-5f);
    float4 gv = ((const float4*)g)[t], bv = ((const float4*)b)[t];
    float4 o;
    o.x = (v.x - mean) * inv * gv.x + bv.x;
    o.y = (v.y - mean) * inv * gv.y + bv.y;
    o.z = (v.z - mean) * inv * gv.z + bv.z;
    o.w = (v.w - mean) * inv * gv.w + bv.w;
    ((float4*)(of + (size_t)row * 1024))[t] = o;
    if (WB) {
        ushort4 u; u.x = f2bf(o.x); u.y = f2bf(o.y); u.z = f2bf(o.z); u.w = f2bf(o.w);
        ((ushort4*)(ob + (size_t)row * 1024))[t] = u;
    }
}

extern "C" void kernel_launch(void* const* d_in, const int* in_sizes, int n_in,
                              void* d_out, int out_size, void* d_ws, size_t ws_size,
                              hipStream_t stream) {
    (void)in_sizes; (void)n_in; (void)out_size; (void)ws_size;
    const float* x          = (const float*)d_in[0];
    const float* step_embed = (const float*)d_in[1];
    const float* qkv_w      = (const float*)d_in[2];
    const float* qkv_b      = (const float*)d_in[3];
    const float* out_w      = (const float*)d_in[4];
    const float* out_b      = (const float*)d_in[5];
    const float* relb       = (const float*)d_in[6];
    const float* w1         = (const float*)d_in[7];
    const float* b1         = (const float*)d_in[8];
    const float* w2         = (const float*)d_in[9];
    const float* b2         = (const float*)d_in[10];
    const float* ln1g       = (const float*)d_in[11];
    const float* ln1b       = (const float*)d_in[12];
    const float* ln2g       = (const float*)d_in[13];
    const float* ln2b       = (const float*)d_in[14];
    const int*   tstep      = (const int*)d_in[15];
    float* out = (float*)d_out;

    char* p = (char*)d_ws;
    u16* wt_qkv = (u16*)p; p += (size_t)3072 * 1024 * 2;
    u16* wt_out = (u16*)p; p += (size_t)1024 * 1024 * 2;
    u16* wt_w1  = (u16*)p; p += (size_t)4096 * 1024 * 2;
    u16* wt_w2  = (u16*)p; p += (size_t)1024 * 4096 * 2;
    float* xse  = (float*)p; p += (size_t)8192 * 1024 * 4;
    u16* xseb   = (u16*)p; p += (size_t)8192 * 1024 * 2;
    u16* qbuf   = (u16*)p; p += (size_t)8192 * 1024 * 2;
    u16* kbuf   = (u16*)p; p += (size_t)8192 * 1024 * 2;
    u16* attnb  = (u16*)p; p += (size_t)8192 * 1024 * 2;
    float* res1 = (float*)p; p += (size_t)8192 * 1024 * 4;
    // aliases (lifetimes disjoint):
    float* y1   = xse;            // x_se dead after out-proj residual
    u16*   y1b  = xseb;           // x_se_bf16 dead after QKV GEMM
    u16*   hbuf = qbuf;           // q/k/attn dead after out-proj GEMM
    float* res2 = res1;           // res1 dead after LN1
    u16*   vtb  = (u16*)res1;     // V^T (written by QKV epilogue) lives until attn; res1 written after attn

    prep_k<<<dim3(12288 + 8192), dim3(256), 0, stream>>>(qkv_w, wt_qkv, out_w, wt_out,
                                                         w1, wt_w1, w2, wt_w2,
                                                         x, step_embed, tstep, xse, xseb);
    gemm_bt<0><<<dim3(64, 24), dim3(256), 0, stream>>>(xseb, wt_qkv, qkv_b, 1024,
                                                       qbuf, kbuf, vtb, (const float*)nullptr, (float*)nullptr);
    attn_k<<<dim3(128, 8), dim3(256), 0, stream>>>(qbuf, kbuf, vtb, relb, attnb);
    gemm_bt<1><<<dim3(64, 8), dim3(256), 0, stream>>>(attnb, wt_out, out_b, 1024,
                                                      (u16*)nullptr, (u16*)nullptr, (u16*)nullptr, xse, res1);
    ln_k<true><<<dim3(8192), dim3(256), 0, stream>>>(res1, ln1g, ln1b, y1, y1b);
    gemm_bt<2><<<dim3(64, 32), dim3(256), 0, stream>>>(y1b, wt_w1, b1, 1024,
                                                       hbuf, (u16*)nullptr, (u16*)nullptr, (const float*)nullptr, (float*)nullptr);
    gemm_bt<3><<<dim3(64, 8), dim3(256), 0, stream>>>(hbuf, wt_w2, b2, 4096,
                                                      (u16*)nullptr, (u16*)nullptr, (u16*)nullptr, y1, res2);
    ln_k<false><<<dim3(8192), dim3(256), 0, stream>>>(res2, ln2g, ln2b, out, (u16*)nullptr);
}